// Round 2
// baseline (1483.078 us; speedup 1.0000x reference)
//
#include <hip/hip_runtime.h>
#include <hip/hip_bf16.h>

// R2: batch x hidden-slice decomposition.
//  - 64 blocks = 8 batches x 8 slices of 16 hid cols; each block owns ALL 128 s-rows
//    -> spatial coupling (h_after/h_before) and In-chain are block-local.
//  - z weights: gate-major permuted WTc2[col''][384], col'' = n*64 + g*16 + h.
//    kt 0..7 in VGPRs (128 regs), kt 8..11 in LDS -> NO per-step weight streaming.
//  - per-step exchange: publish own 128x16 h-slice (relaxed agent atomics) ->
//    vmcnt(0) -> barrier -> release fence -> flag; readers poll flag -> acquire
//    fence -> relaxed atomic gathers. No seq_cst fence (R1's buffer_inv killer).

#define NB 8
#define NT 128
#define NS 128
#define NSTEP 127
#define TPRED 4
#define TOUT 123

typedef __attribute__((ext_vector_type(4))) float f32x4;
typedef __attribute__((ext_vector_type(8))) short s16x8;

// workspace layout (bytes)
#define WS_WTC 0                        // bf16 [512][384]: col''=n*64+g*16+h, K=[h_before,h,h_after]
#define WS_WT1 (512*384*2)              // bf16 [128][128]: [out_col][k]
#define WS_HB  (WS_WT1 + 128*128*2)     // bf16 [2 parity][8 b][8 slice][128 row][16 col]
#define WS_FLG (WS_HB + 2*64*2048*2)    // u32 [64] step flags

__device__ __forceinline__ unsigned swz(unsigned off) {
    // XOR-swizzle for 256B-stride bf16 LDS tiles (G4)
    return off ^ (((off >> 8) & 7u) << 4);
}

__global__ void init_weights(const float* __restrict__ Wc, const float* __restrict__ W1,
                             __hip_bfloat16* __restrict__ WTc, __hip_bfloat16* __restrict__ WT1)
{
    int i = blockIdx.x * blockDim.x + threadIdx.x;
    if (i < 512*384) {
        int cpp = i / 384, k = i % 384;
        int n = cpp >> 6, rem = cpp & 63, g = rem >> 4, h = rem & 15;
        int oc = g*128 + 16*n + h;   // original W_cell column
        int row = (k < 128) ? (261 + k) : ((k < 256) ? (5 + (k - 128)) : (133 + (k - 256)));
        WTc[cpp*384 + k] = __float2bfloat16(Wc[row*512 + oc]);
    } else {
        int q = i - 512*384;
        if (q < 128*128) {
            int nn = q >> 7, k = q & 127;
            WT1[nn*128 + k] = __float2bfloat16(W1[k*128 + nn]);
        }
    }
}

__global__ __launch_bounds__(512, 2) void lstm_persist(
    const float* __restrict__ input, const float* __restrict__ Wc,
    const float* __restrict__ bc, const float* __restrict__ b1v,
    const float* __restrict__ W2, const float* __restrict__ b2,
    float* __restrict__ outp,
    const __hip_bfloat16* __restrict__ WTc, const __hip_bfloat16* __restrict__ WT1,
    unsigned short* hbu, unsigned* flags)
{
    __shared__ __align__(16) __hip_bfloat16 h_loc[130*128];  // rows: 0 = s=-1 pad, 1..128 = h, 129 = s=128 pad (swz)
    __shared__ __align__(16) __hip_bfloat16 bl[64*136];      // z-weights kt 8..11: [col 0..63][128k], stride 272B
    __shared__ __align__(16) __hip_bfloat16 relu_l[18*128];  // swz, local rows 0..16
    __shared__ float xl[2][640];    // x(t) staging, parity dbuf
    __shared__ float xnl[2][3];     // x(t)[s=0][{1,3,4}]
    __shared__ float outl[17*3];    // out rows 16n-1 .. 16n+15
    __shared__ float w2l[3*128];
    __shared__ float b2l[3];

    const int tid  = threadIdx.x;
    const int blk  = blockIdx.x;
    const int b    = blk & 7;       // batch
    const int n    = blk >> 3;      // hid slice (siblings of a batch share blk%8 -> likely same XCD)
    const int lane = tid & 63;
    const int w    = tid >> 6;      // wave 0..7 = M-tile (16 s-rows)
    const int arow = lane & 15;
    const int kgrp = lane >> 4;
    const int hid  = 16*n + arow;   // hid column this lane owns in gate phase

    for (int i = tid; i < 130*128; i += 512) ((unsigned short*)h_loc)[i] = 0;
    if (tid < 384) w2l[tid] = W2[(tid & 127)*3 + (tid >> 7)];
    if (tid >= 384 && tid < 387) b2l[tid - 384] = b2[tid - 384];
    // stage LDS part of z-weights (k 256..383)
    for (int i = tid; i < 64*32; i += 512) {
        int col = i >> 5, kk = i & 31;
        *(unsigned long long*)((char*)bl + col*272 + kk*8) =
            *(const unsigned long long*)((const char*)WTc + ((unsigned)(n*64 + col)*384 + 256)*2 + kk*8);
    }

    // per-lane constants
    float wxr[4][5], bcr[4];
    #pragma unroll
    for (int g = 0; g < 4; ++g) {
        const int cg = g*128 + hid;
        bcr[g] = bc[cg];
        #pragma unroll
        for (int f = 0; f < 5; ++f) wxr[g][f] = Wc[f*512 + cg];
    }
    const float b1r = b1v[16*w + arow];

    // register-resident z-weights (kt 0..7) and W1 fragments
    s16x8 brg[4][8];
    #pragma unroll
    for (int g = 0; g < 4; ++g)
        #pragma unroll
        for (int kt = 0; kt < 8; ++kt)
            brg[g][kt] = *(const s16x8*)((const char*)WTc +
                ((unsigned)(n*64 + g*16 + arow)*384 + kt*32 + kgrp*8)*2);
    s16x8 w1r[4];
    #pragma unroll
    for (int kt = 0; kt < 4; ++kt)
        w1r[kt] = *(const s16x8*)((const char*)WT1 + ((unsigned)(16*w + arow)*128 + kt*32 + kgrp*8)*2);

    float cst[4] = {0.f, 0.f, 0.f, 0.f};
    unsigned short hregb[4] = {0, 0, 0, 0};
    unsigned* myflag = flags + b*8 + n;

    __syncthreads();

    for (int j = 0; j <= NSTEP; ++j) {
        // ---- stage x(j) ----
        {
            const float* xp = input + (unsigned)(b*NT + j)*640;
            xl[j&1][tid] = xp[tid];
            if (tid < 128) xl[j&1][512 + tid] = xp[512 + tid];
            if (tid >= 509 && tid < 512) { int q = tid - 509; xnl[j&1][q] = xp[(q == 0) ? 1 : (q + 2)]; }
        }
        // ---- C: sync + gather h(j) ----
        if (j > 0) {
            if (tid < 7) {
                const int sp = tid + (tid >= n);
                const unsigned* f = flags + b*8 + sp;
                while (__hip_atomic_load(f, __ATOMIC_RELAXED, __HIP_MEMORY_SCOPE_AGENT) < (unsigned)j)
                    __builtin_amdgcn_s_sleep(2);
            }
            __syncthreads();
            __builtin_amdgcn_fence(__ATOMIC_ACQUIRE, "agent");
            const unsigned long long* hb64 =
                (const unsigned long long*)hbu + (unsigned)((j&1)*64 + b*8)*512;
            #pragma unroll
            for (int s7 = 0; s7 < 7; ++s7) {
                const int sp = s7 + (s7 >= n);
                unsigned long long v = __hip_atomic_load(hb64 + sp*512 + tid,
                                                         __ATOMIC_RELAXED, __HIP_MEMORY_SCOPE_AGENT);
                *(unsigned long long*)((char*)h_loc +
                    swz((unsigned)(((tid>>2) + 1)*256 + (16*sp + 4*(tid&3))*2))) = v;
            }
            #pragma unroll
            for (int r = 0; r < 4; ++r)
                *(unsigned short*)((char*)h_loc +
                    swz((unsigned)((16*w + kgrp*4 + r + 1)*256 + hid*2))) = hregb[r];
        }
        __syncthreads();  // B1: h_loc = full h(j), xl staged

        // ---- A: z-GEMM M=128 N=64 K=384 + gates -> h(j+1) slice; publish ----
        if (j < NSTEP) {
            f32x4 a0 = {0.f,0.f,0.f,0.f}, a1 = a0, a2 = a0, a3 = a0;
            const unsigned abase = (unsigned)((16*w + arow)*256 + kgrp*16);
            #pragma unroll
            for (int kt = 0; kt < 8; ++kt) {
                const s16x8 av = *(const s16x8*)((const char*)h_loc + swz(abase + kt*64));
                a0 = __builtin_amdgcn_mfma_f32_16x16x32_bf16(av, brg[0][kt], a0, 0, 0, 0);
                a1 = __builtin_amdgcn_mfma_f32_16x16x32_bf16(av, brg[1][kt], a1, 0, 0, 0);
                a2 = __builtin_amdgcn_mfma_f32_16x16x32_bf16(av, brg[2][kt], a2, 0, 0, 0);
                a3 = __builtin_amdgcn_mfma_f32_16x16x32_bf16(av, brg[3][kt], a3, 0, 0, 0);
            }
            #pragma unroll
            for (int kt = 8; kt < 12; ++kt) {
                const s16x8 av = *(const s16x8*)((const char*)h_loc + swz(abase + kt*64));
                const char* blb = (const char*)bl + (kt - 8)*64 + kgrp*16;
                a0 = __builtin_amdgcn_mfma_f32_16x16x32_bf16(av, *(const s16x8*)(blb + (arow      )*272), a0, 0, 0, 0);
                a1 = __builtin_amdgcn_mfma_f32_16x16x32_bf16(av, *(const s16x8*)(blb + (16 + arow )*272), a1, 0, 0, 0);
                a2 = __builtin_amdgcn_mfma_f32_16x16x32_bf16(av, *(const s16x8*)(blb + (32 + arow )*272), a2, 0, 0, 0);
                a3 = __builtin_amdgcn_mfma_f32_16x16x32_bf16(av, *(const s16x8*)(blb + (48 + arow )*272), a3, 0, 0, 0);
            }
            unsigned short* pub = hbu + (unsigned)(((j+1)&1)*64 + b*8 + n)*2048;
            #pragma unroll
            for (int r = 0; r < 4; ++r) {
                const int row = 16*w + kgrp*4 + r;
                const float xv0 = xl[j&1][row*5+0], xv1 = xl[j&1][row*5+1], xv2 = xl[j&1][row*5+2],
                            xv3 = xl[j&1][row*5+3], xv4 = xl[j&1][row*5+4];
                const float iv = a0[r] + bcr[0] + xv0*wxr[0][0] + xv1*wxr[0][1] + xv2*wxr[0][2] + xv3*wxr[0][3] + xv4*wxr[0][4];
                const float fv = a1[r] + bcr[1] + xv0*wxr[1][0] + xv1*wxr[1][1] + xv2*wxr[1][2] + xv3*wxr[1][3] + xv4*wxr[1][4];
                const float gv = a2[r] + bcr[2] + xv0*wxr[2][0] + xv1*wxr[2][1] + xv2*wxr[2][2] + xv3*wxr[2][3] + xv4*wxr[2][4];
                const float ov = a3[r] + bcr[3] + xv0*wxr[3][0] + xv1*wxr[3][1] + xv2*wxr[3][2] + xv3*wxr[3][3] + xv4*wxr[3][4];
                const float si = __builtin_amdgcn_rcpf(1.f + __expf(-iv));
                const float sf = __builtin_amdgcn_rcpf(1.f + __expf(-fv));
                const float so = __builtin_amdgcn_rcpf(1.f + __expf(-ov));
                const float tg = 1.f - 2.f*__builtin_amdgcn_rcpf(__expf(2.f*gv) + 1.f);
                const float cn = sf*cst[r] + si*tg;
                cst[r] = cn;
                const float tc = 1.f - 2.f*__builtin_amdgcn_rcpf(__expf(2.f*cn) + 1.f);
                const float hn = so*tc;
                __hip_bfloat16 hb = __float2bfloat16(hn);
                unsigned short hbits = *(unsigned short*)&hb;
                hregb[r] = hbits;
                __hip_atomic_store(pub + row*16 + arow, hbits, __ATOMIC_RELAXED, __HIP_MEMORY_SCOPE_AGENT);
            }
            asm volatile("s_waitcnt vmcnt(0)" ::: "memory");
            __syncthreads();  // B2: all publishes complete
            if (tid == 0) {
                __builtin_amdgcn_fence(__ATOMIC_RELEASE, "agent");
                __hip_atomic_store(myflag, (unsigned)(j + 1), __ATOMIC_RELAXED, __HIP_MEMORY_SCOPE_AGENT);
            }
        }

        // ---- D: out(j-1) from h(j) for owned rows [16n, 16n+16) (+row 16n-1 for In) ----
        if (j >= TPRED + 1) {
            f32x4 c0 = {0.f,0.f,0.f,0.f}, c1 = c0;
            const unsigned w1a = (unsigned)((16*n + arow)*256 + kgrp*16);
            #pragma unroll
            for (int kt = 0; kt < 4; ++kt) {
                const s16x8 av0 = *(const s16x8*)((const char*)h_loc + swz(w1a + kt*64));         // rows 16n-1+arow
                const s16x8 av1 = *(const s16x8*)((const char*)h_loc + swz(w1a + 256 + kt*64));   // rows 16n+arow
                c0 = __builtin_amdgcn_mfma_f32_16x16x32_bf16(av0, w1r[kt], c0, 0, 0, 0);
                c1 = __builtin_amdgcn_mfma_f32_16x16x32_bf16(av1, w1r[kt], c1, 0, 0, 0);
            }
            #pragma unroll
            for (int r = 0; r < 4; ++r) {
                const int lr = kgrp*4 + r;    // local row 0..15 (global 16n-1+lr)
                const float v0 = fmaxf(c0[r] + b1r, 0.f);
                *(__hip_bfloat16*)((char*)relu_l + swz((unsigned)(lr*256 + (16*w + arow)*2))) = __float2bfloat16(v0);
                if (lr == 15) {               // only c1 can produce local row 16
                    const float v1 = fmaxf(c1[r] + b1r, 0.f);
                    *(__hip_bfloat16*)((char*)relu_l + swz((unsigned)(16*256 + (16*w + arow)*2))) = __float2bfloat16(v1);
                }
            }
            __syncthreads();  // B3
            if (tid < 51) {
                const int m = tid / 3, p = tid - m*3;
                float s = b2l[p];
                #pragma unroll
                for (int kc = 0; kc < 16; ++kc) {
                    union { s16x8 v; unsigned short u[8]; } uu;
                    uu.v = *(const s16x8*)((const char*)relu_l + swz((unsigned)(m*256 + kc*16)));
                    #pragma unroll
                    for (int e = 0; e < 8; ++e)
                        s += __uint_as_float((unsigned)uu.u[e] << 16) * w2l[p*128 + kc*8 + e];
                }
                outl[m*3 + p] = s;
            }
            __syncthreads();  // B4
            if (tid < 16) {
                const int m = tid, grow = 16*n + m;
                const float no = outl[(m + 1)*3 + 0];
                float In, sp0, sp1;
                if (m == 0 && n == 0) { In = xnl[j&1][0]; sp0 = xnl[j&1][1]; sp1 = xnl[j&1][2]; }
                else { In = outl[m*3 + 0]; sp0 = outl[(m + 1)*3 + 1]; sp1 = outl[(m + 1)*3 + 2]; }
                const float former = xl[(j - 1)&1][grow*5 + 2];
                const long base = ((long)(b*TOUT + (j - 1 - TPRED))*NS + grow)*5;
                outp[base + 0] = no;
                outp[base + 1] = In;
                outp[base + 2] = former + In - no;
                outp[base + 3] = sp0;
                outp[base + 4] = sp1;
            }
        }
        __syncthreads();  // B0: protect xl/h_loc/outl for next iteration
    }
}

extern "C" void kernel_launch(void* const* d_in, const int* in_sizes, int n_in,
                              void* d_out, int out_size, void* d_ws, size_t ws_size,
                              hipStream_t stream) {
    const float* input = (const float*)d_in[0];
    const float* Wc    = (const float*)d_in[1];
    const float* bc    = (const float*)d_in[2];
    const float* W1    = (const float*)d_in[3];
    const float* b1    = (const float*)d_in[4];
    const float* W2    = (const float*)d_in[5];
    const float* b2    = (const float*)d_in[6];
    float* outp = (float*)d_out;
    char* ws = (char*)d_ws;

    __hip_bfloat16* WTc = (__hip_bfloat16*)(ws + WS_WTC);
    __hip_bfloat16* WT1 = (__hip_bfloat16*)(ws + WS_WT1);
    unsigned short* hb  = (unsigned short*)(ws + WS_HB);
    unsigned*       flg = (unsigned*)(ws + WS_FLG);

    hipMemsetAsync(ws + WS_FLG, 0, 64*4, stream);
    init_weights<<<832, 256, 0, stream>>>(Wc, W1, WTc, WT1);
    lstm_persist<<<64, 512, 0, stream>>>(input, Wc, bc, b1, W2, b2, outp, WTc, WT1, hb, flg);
}

// Round 3
// 950.741 us; speedup vs baseline: 1.5599x; 1.5599x over previous
//
#include <hip/hip_runtime.h>
#include <hip/hip_bf16.h>

// R3 = R2 minus agent fences. Cross-block h exchange uses explicit sc0|sc1
// (LLC-coherent, L1/L2-bypass) loads/stores via inline asm; ordering via
// s_waitcnt vmcnt(0) + barrier before flag. No buffer_wbl2 / buffer_inv.

#define NB 8
#define NT 128
#define NS 128
#define NSTEP 127
#define TPRED 4
#define TOUT 123

typedef __attribute__((ext_vector_type(4))) float f32x4;
typedef __attribute__((ext_vector_type(8))) short s16x8;

// workspace layout (bytes)
#define WS_WTC 0                        // bf16 [512][384]: col''=n*64+g*16+h, K=[h_before,h,h_after]
#define WS_WT1 (512*384*2)              // bf16 [128][128]: [out_col][k]
#define WS_HB  (WS_WT1 + 128*128*2)     // bf16 [2 parity][8 b][8 slice][128 row][16 col]
#define WS_FLG (WS_HB + 2*64*2048*2)    // u32 [64] step flags

__device__ __forceinline__ unsigned swz(unsigned off) {
    return off ^ (((off >> 8) & 7u) << 4);
}

__device__ __forceinline__ void st16_llc(void* p, unsigned v) {
    asm volatile("global_store_short %0, %1, off sc0 sc1" :: "v"(p), "v"(v) : "memory");
}
__device__ __forceinline__ void st32_llc(void* p, unsigned v) {
    asm volatile("global_store_dword %0, %1, off sc0 sc1" :: "v"(p), "v"(v) : "memory");
}
__device__ __forceinline__ unsigned ld32_llc(const void* p) {
    unsigned v;
    asm volatile("global_load_dword %0, %1, off sc0 sc1\n\ts_waitcnt vmcnt(0)"
                 : "=v"(v) : "v"(p) : "memory");
    return v;
}

__global__ void init_weights(const float* __restrict__ Wc, const float* __restrict__ W1,
                             __hip_bfloat16* __restrict__ WTc, __hip_bfloat16* __restrict__ WT1)
{
    int i = blockIdx.x * blockDim.x + threadIdx.x;
    if (i < 512*384) {
        int cpp = i / 384, k = i % 384;
        int n = cpp >> 6, rem = cpp & 63, g = rem >> 4, h = rem & 15;
        int oc = g*128 + 16*n + h;   // original W_cell column
        int row = (k < 128) ? (261 + k) : ((k < 256) ? (5 + (k - 128)) : (133 + (k - 256)));
        WTc[cpp*384 + k] = __float2bfloat16(Wc[row*512 + oc]);
    } else {
        int q = i - 512*384;
        if (q < 128*128) {
            int nn = q >> 7, k = q & 127;
            WT1[nn*128 + k] = __float2bfloat16(W1[k*128 + nn]);
        }
    }
}

__global__ __launch_bounds__(512, 2) void lstm_persist(
    const float* __restrict__ input, const float* __restrict__ Wc,
    const float* __restrict__ bc, const float* __restrict__ b1v,
    const float* __restrict__ W2, const float* __restrict__ b2,
    float* __restrict__ outp,
    const __hip_bfloat16* __restrict__ WTc, const __hip_bfloat16* __restrict__ WT1,
    unsigned short* hbu, unsigned* flags)
{
    __shared__ __align__(16) __hip_bfloat16 h_loc[130*128];  // rows: 0 = s=-1 pad, 1..128 = h, 129 = s=128 pad (swz)
    __shared__ __align__(16) __hip_bfloat16 bl[64*136];      // z-weights kt 8..11: [col 0..63][128k], stride 272B
    __shared__ __align__(16) __hip_bfloat16 relu_l[18*128];  // swz, local rows 0..16
    __shared__ float xl[2][640];    // x(t) staging, parity dbuf
    __shared__ float xnl[2][3];     // x(t)[s=0][{1,3,4}]
    __shared__ float outl[17*3];    // out rows 16n-1 .. 16n+15
    __shared__ float w2l[3*128];
    __shared__ float b2l[3];

    const int tid  = threadIdx.x;
    const int blk  = blockIdx.x;
    const int b    = blk & 7;       // batch
    const int n    = blk >> 3;      // hid slice
    const int lane = tid & 63;
    const int w    = tid >> 6;      // wave 0..7 = M-tile (16 s-rows)
    const int arow = lane & 15;
    const int kgrp = lane >> 4;
    const int hid  = 16*n + arow;   // hid column this lane owns in gate phase

    for (int i = tid; i < 130*128; i += 512) ((unsigned short*)h_loc)[i] = 0;
    if (tid < 384) w2l[tid] = W2[(tid & 127)*3 + (tid >> 7)];
    if (tid >= 384 && tid < 387) b2l[tid - 384] = b2[tid - 384];
    // stage LDS part of z-weights (k 256..383)
    for (int i = tid; i < 64*32; i += 512) {
        int col = i >> 5, kk = i & 31;
        *(unsigned long long*)((char*)bl + col*272 + kk*8) =
            *(const unsigned long long*)((const char*)WTc + ((unsigned)(n*64 + col)*384 + 256)*2 + kk*8);
    }

    // per-lane constants
    float wxr[4][5], bcr[4];
    #pragma unroll
    for (int g = 0; g < 4; ++g) {
        const int cg = g*128 + hid;
        bcr[g] = bc[cg];
        #pragma unroll
        for (int f = 0; f < 5; ++f) wxr[g][f] = Wc[f*512 + cg];
    }
    const float b1r = b1v[16*w + arow];

    // register-resident z-weights (kt 0..7) and W1 fragments
    s16x8 brg[4][8];
    #pragma unroll
    for (int g = 0; g < 4; ++g)
        #pragma unroll
        for (int kt = 0; kt < 8; ++kt)
            brg[g][kt] = *(const s16x8*)((const char*)WTc +
                ((unsigned)(n*64 + g*16 + arow)*384 + kt*32 + kgrp*8)*2);
    s16x8 w1r[4];
    #pragma unroll
    for (int kt = 0; kt < 4; ++kt)
        w1r[kt] = *(const s16x8*)((const char*)WT1 + ((unsigned)(16*w + arow)*128 + kt*32 + kgrp*8)*2);

    float cst[4] = {0.f, 0.f, 0.f, 0.f};
    unsigned short hregb[4] = {0, 0, 0, 0};
    unsigned* myflag = flags + b*8 + n;

    __syncthreads();

    for (int j = 0; j <= NSTEP; ++j) {
        // ---- stage x(j) ----
        {
            const float* xp = input + (unsigned)(b*NT + j)*640;
            xl[j&1][tid] = xp[tid];
            if (tid < 128) xl[j&1][512 + tid] = xp[512 + tid];
            if (tid >= 509 && tid < 512) { int q = tid - 509; xnl[j&1][q] = xp[(q == 0) ? 1 : (q + 2)]; }
        }
        // ---- C: sync + gather h(j) (LLC-coherent loads, no fences) ----
        if (j > 0) {
            if (tid < 7) {
                const int sp = tid + (tid >= n);
                const unsigned* f = flags + b*8 + sp;
                while (ld32_llc(f) < (unsigned)j)
                    __builtin_amdgcn_s_sleep(1);
            }
            __syncthreads();
            const unsigned long long* hb64 =
                (const unsigned long long*)hbu + (unsigned)((j&1)*64 + b*8)*512;
            const int s_0 = 0 + (0 >= n), s_1 = 1 + (1 >= n), s_2 = 2 + (2 >= n), s_3 = 3 + (3 >= n),
                      s_4 = 4 + (4 >= n), s_5 = 5 + (5 >= n), s_6 = 6 + (6 >= n);
            const unsigned long long *q0 = hb64 + s_0*512 + tid, *q1 = hb64 + s_1*512 + tid,
                                     *q2 = hb64 + s_2*512 + tid, *q3 = hb64 + s_3*512 + tid,
                                     *q4 = hb64 + s_4*512 + tid, *q5 = hb64 + s_5*512 + tid,
                                     *q6 = hb64 + s_6*512 + tid;
            unsigned long long g0, g1, g2, g3, g4, g5, g6;
            asm volatile(
                "global_load_dwordx2 %0, %7, off sc0 sc1\n\t"
                "global_load_dwordx2 %1, %8, off sc0 sc1\n\t"
                "global_load_dwordx2 %2, %9, off sc0 sc1\n\t"
                "global_load_dwordx2 %3, %10, off sc0 sc1\n\t"
                "global_load_dwordx2 %4, %11, off sc0 sc1\n\t"
                "global_load_dwordx2 %5, %12, off sc0 sc1\n\t"
                "global_load_dwordx2 %6, %13, off sc0 sc1\n\t"
                "s_waitcnt vmcnt(0)"
                : "=&v"(g0), "=&v"(g1), "=&v"(g2), "=&v"(g3), "=&v"(g4), "=&v"(g5), "=&v"(g6)
                : "v"(q0), "v"(q1), "v"(q2), "v"(q3), "v"(q4), "v"(q5), "v"(q6)
                : "memory");
            __builtin_amdgcn_sched_barrier(0);
            const unsigned rb = (unsigned)(((tid >> 2) + 1)*256);
            const unsigned cb = (unsigned)(4*(tid & 3))*2u;
            *(unsigned long long*)((char*)h_loc + swz(rb + 32u*s_0 + cb)) = g0;
            *(unsigned long long*)((char*)h_loc + swz(rb + 32u*s_1 + cb)) = g1;
            *(unsigned long long*)((char*)h_loc + swz(rb + 32u*s_2 + cb)) = g2;
            *(unsigned long long*)((char*)h_loc + swz(rb + 32u*s_3 + cb)) = g3;
            *(unsigned long long*)((char*)h_loc + swz(rb + 32u*s_4 + cb)) = g4;
            *(unsigned long long*)((char*)h_loc + swz(rb + 32u*s_5 + cb)) = g5;
            *(unsigned long long*)((char*)h_loc + swz(rb + 32u*s_6 + cb)) = g6;
            #pragma unroll
            for (int r = 0; r < 4; ++r)
                *(unsigned short*)((char*)h_loc +
                    swz((unsigned)((16*w + kgrp*4 + r + 1)*256 + hid*2))) = hregb[r];
        }
        __syncthreads();  // B1: h_loc = full h(j), xl staged

        // ---- A: z-GEMM M=128 N=64 K=384 + gates -> h(j+1) slice; publish ----
        if (j < NSTEP) {
            f32x4 a0 = {0.f,0.f,0.f,0.f}, a1 = a0, a2 = a0, a3 = a0;
            const unsigned abase = (unsigned)((16*w + arow)*256 + kgrp*16);
            #pragma unroll
            for (int kt = 0; kt < 8; ++kt) {
                const s16x8 av = *(const s16x8*)((const char*)h_loc + swz(abase + kt*64));
                a0 = __builtin_amdgcn_mfma_f32_16x16x32_bf16(av, brg[0][kt], a0, 0, 0, 0);
                a1 = __builtin_amdgcn_mfma_f32_16x16x32_bf16(av, brg[1][kt], a1, 0, 0, 0);
                a2 = __builtin_amdgcn_mfma_f32_16x16x32_bf16(av, brg[2][kt], a2, 0, 0, 0);
                a3 = __builtin_amdgcn_mfma_f32_16x16x32_bf16(av, brg[3][kt], a3, 0, 0, 0);
            }
            #pragma unroll
            for (int kt = 8; kt < 12; ++kt) {
                const s16x8 av = *(const s16x8*)((const char*)h_loc + swz(abase + kt*64));
                const char* blb = (const char*)bl + (kt - 8)*64 + kgrp*16;
                a0 = __builtin_amdgcn_mfma_f32_16x16x32_bf16(av, *(const s16x8*)(blb + (arow      )*272), a0, 0, 0, 0);
                a1 = __builtin_amdgcn_mfma_f32_16x16x32_bf16(av, *(const s16x8*)(blb + (16 + arow )*272), a1, 0, 0, 0);
                a2 = __builtin_amdgcn_mfma_f32_16x16x32_bf16(av, *(const s16x8*)(blb + (32 + arow )*272), a2, 0, 0, 0);
                a3 = __builtin_amdgcn_mfma_f32_16x16x32_bf16(av, *(const s16x8*)(blb + (48 + arow )*272), a3, 0, 0, 0);
            }
            unsigned short* pub = hbu + (unsigned)(((j+1)&1)*64 + b*8 + n)*2048;
            #pragma unroll
            for (int r = 0; r < 4; ++r) {
                const int row = 16*w + kgrp*4 + r;
                const float xv0 = xl[j&1][row*5+0], xv1 = xl[j&1][row*5+1], xv2 = xl[j&1][row*5+2],
                            xv3 = xl[j&1][row*5+3], xv4 = xl[j&1][row*5+4];
                const float iv = a0[r] + bcr[0] + xv0*wxr[0][0] + xv1*wxr[0][1] + xv2*wxr[0][2] + xv3*wxr[0][3] + xv4*wxr[0][4];
                const float fv = a1[r] + bcr[1] + xv0*wxr[1][0] + xv1*wxr[1][1] + xv2*wxr[1][2] + xv3*wxr[1][3] + xv4*wxr[1][4];
                const float gv = a2[r] + bcr[2] + xv0*wxr[2][0] + xv1*wxr[2][1] + xv2*wxr[2][2] + xv3*wxr[2][3] + xv4*wxr[2][4];
                const float ov = a3[r] + bcr[3] + xv0*wxr[3][0] + xv1*wxr[3][1] + xv2*wxr[3][2] + xv3*wxr[3][3] + xv4*wxr[3][4];
                const float si = __builtin_amdgcn_rcpf(1.f + __expf(-iv));
                const float sf = __builtin_amdgcn_rcpf(1.f + __expf(-fv));
                const float so = __builtin_amdgcn_rcpf(1.f + __expf(-ov));
                const float tg = 1.f - 2.f*__builtin_amdgcn_rcpf(__expf(2.f*gv) + 1.f);
                const float cn = sf*cst[r] + si*tg;
                cst[r] = cn;
                const float tc = 1.f - 2.f*__builtin_amdgcn_rcpf(__expf(2.f*cn) + 1.f);
                const float hn = so*tc;
                __hip_bfloat16 hbv = __float2bfloat16(hn);
                unsigned short hbits = *(unsigned short*)&hbv;
                hregb[r] = hbits;
                st16_llc(pub + row*16 + arow, (unsigned)hbits);
            }
            asm volatile("s_waitcnt vmcnt(0)" ::: "memory");
            __syncthreads();  // B2: all publishes at LLC
            if (tid == 0)
                st32_llc(myflag, (unsigned)(j + 1));
        }

        // ---- D: out(j-1) from h(j) for owned rows [16n, 16n+16) (+row 16n-1 for In) ----
        if (j >= TPRED + 1) {
            f32x4 c0 = {0.f,0.f,0.f,0.f}, c1 = c0;
            const unsigned w1a = (unsigned)((16*n + arow)*256 + kgrp*16);
            #pragma unroll
            for (int kt = 0; kt < 4; ++kt) {
                const s16x8 av0 = *(const s16x8*)((const char*)h_loc + swz(w1a + kt*64));         // rows 16n-1+arow
                const s16x8 av1 = *(const s16x8*)((const char*)h_loc + swz(w1a + 256 + kt*64));   // rows 16n+arow
                c0 = __builtin_amdgcn_mfma_f32_16x16x32_bf16(av0, w1r[kt], c0, 0, 0, 0);
                c1 = __builtin_amdgcn_mfma_f32_16x16x32_bf16(av1, w1r[kt], c1, 0, 0, 0);
            }
            #pragma unroll
            for (int r = 0; r < 4; ++r) {
                const int lr = kgrp*4 + r;    // local row 0..15 (global 16n-1+lr)
                const float v0 = fmaxf(c0[r] + b1r, 0.f);
                *(__hip_bfloat16*)((char*)relu_l + swz((unsigned)(lr*256 + (16*w + arow)*2))) = __float2bfloat16(v0);
                if (lr == 15) {               // only c1 can produce local row 16
                    const float v1 = fmaxf(c1[r] + b1r, 0.f);
                    *(__hip_bfloat16*)((char*)relu_l + swz((unsigned)(16*256 + (16*w + arow)*2))) = __float2bfloat16(v1);
                }
            }
            __syncthreads();  // B3
            if (tid < 51) {
                const int m = tid / 3, p = tid - m*3;
                float s = b2l[p];
                #pragma unroll
                for (int kc = 0; kc < 16; ++kc) {
                    union { s16x8 v; unsigned short u[8]; } uu;
                    uu.v = *(const s16x8*)((const char*)relu_l + swz((unsigned)(m*256 + kc*16)));
                    #pragma unroll
                    for (int e = 0; e < 8; ++e)
                        s += __uint_as_float((unsigned)uu.u[e] << 16) * w2l[p*128 + kc*8 + e];
                }
                outl[m*3 + p] = s;
            }
            __syncthreads();  // B4
            if (tid < 16) {
                const int m = tid, grow = 16*n + m;
                const float no = outl[(m + 1)*3 + 0];
                float In, sp0, sp1;
                if (m == 0 && n == 0) { In = xnl[j&1][0]; sp0 = xnl[j&1][1]; sp1 = xnl[j&1][2]; }
                else { In = outl[m*3 + 0]; sp0 = outl[(m + 1)*3 + 1]; sp1 = outl[(m + 1)*3 + 2]; }
                const float former = xl[(j - 1)&1][grow*5 + 2];
                const long base = ((long)(b*TOUT + (j - 1 - TPRED))*NS + grow)*5;
                outp[base + 0] = no;
                outp[base + 1] = In;
                outp[base + 2] = former + In - no;
                outp[base + 3] = sp0;
                outp[base + 4] = sp1;
            }
        }
        __syncthreads();  // B0: protect xl/h_loc/outl for next iteration
    }
}

extern "C" void kernel_launch(void* const* d_in, const int* in_sizes, int n_in,
                              void* d_out, int out_size, void* d_ws, size_t ws_size,
                              hipStream_t stream) {
    const float* input = (const float*)d_in[0];
    const float* Wc    = (const float*)d_in[1];
    const float* bc    = (const float*)d_in[2];
    const float* W1    = (const float*)d_in[3];
    const float* b1    = (const float*)d_in[4];
    const float* W2    = (const float*)d_in[5];
    const float* b2    = (const float*)d_in[6];
    float* outp = (float*)d_out;
    char* ws = (char*)d_ws;

    __hip_bfloat16* WTc = (__hip_bfloat16*)(ws + WS_WTC);
    __hip_bfloat16* WT1 = (__hip_bfloat16*)(ws + WS_WT1);
    unsigned short* hb  = (unsigned short*)(ws + WS_HB);
    unsigned*       flg = (unsigned*)(ws + WS_FLG);

    hipMemsetAsync(ws + WS_FLG, 0, 64*4, stream);
    init_weights<<<832, 256, 0, stream>>>(Wc, W1, WTc, WT1);
    lstm_persist<<<64, 512, 0, stream>>>(input, Wc, bc, b1, W2, b2, outp, WTc, WT1, hb, flg);
}